// Round 3
// baseline (537.443 us; speedup 1.0000x reference)
//
#include <hip/hip_runtime.h>
#include <stdint.h>

#define M_DIM 8192
#define K_DIM 4096
#define N_DIM 4096

typedef int   i32x4 __attribute__((ext_vector_type(4)));
typedef float f32x4 __attribute__((ext_vector_type(4)));

// async global -> LDS, 16B per active lane; LDS dest = wave-uniform base + lane*16
__device__ __forceinline__ void gload16(const void* g, void* l) {
    __builtin_amdgcn_global_load_lds(
        (const __attribute__((address_space(1))) void*)g,
        (__attribute__((address_space(3))) void*)l,
        16, 0, 0);
}

// ---------------- kernel 1: x fp32 -> int8 with per-row scale ----------------
__global__ __launch_bounds__(256) void conv_x_i8(const float* __restrict__ x,
                                                 int* __restrict__ xq,
                                                 float* __restrict__ xs) {
    int m = blockIdx.x, tid = threadIdx.x;
    const float* row = x + (size_t)m * K_DIM;
    float4 v[4];
    float mx = 0.f;
    #pragma unroll
    for (int i = 0; i < 4; ++i) {
        v[i] = *(const float4*)(row + i * 1024 + tid * 4);
        mx = fmaxf(mx, fmaxf(fmaxf(fabsf(v[i].x), fabsf(v[i].y)),
                             fmaxf(fabsf(v[i].z), fabsf(v[i].w))));
    }
    #pragma unroll
    for (int o = 32; o > 0; o >>= 1) mx = fmaxf(mx, __shfl_xor(mx, o, 64));
    __shared__ float red[4];
    if ((tid & 63) == 0) red[tid >> 6] = mx;
    __syncthreads();
    mx = fmaxf(fmaxf(red[0], red[1]), fmaxf(red[2], red[3]));
    mx = fmaxf(mx, 1e-20f);
    float inv = 127.f / mx;
    if (tid == 0) xs[m] = mx * (1.f / 127.f);
    #pragma unroll
    for (int i = 0; i < 4; ++i) {
        int q0 = (int)__builtin_rintf(v[i].x * inv);
        int q1 = (int)__builtin_rintf(v[i].y * inv);
        int q2 = (int)__builtin_rintf(v[i].z * inv);
        int q3 = (int)__builtin_rintf(v[i].w * inv);
        uint32_t p = (uint32_t)(q0 & 255) | ((uint32_t)(q1 & 255) << 8) |
                     ((uint32_t)(q2 & 255) << 16) | ((uint32_t)q3 << 24);
        xq[(size_t)m * (K_DIM / 4) + i * 256 + tid] = (int)p;
    }
}

// ---------------- kernel 2: dequant -> Wt int8 [N, K], value (w - z) ----------------
#define DLROW 272   // 256 + 16 bytes pad
__global__ __launch_bounds__(256) void dequant_i8(const uint32_t* __restrict__ qw,
                                                  const uint32_t* __restrict__ qz,
                                                  const int* __restrict__ gidx,
                                                  signed char* __restrict__ wt) {
    __shared__ __align__(16) unsigned char lds[64 * DLROW];
    int tid = threadIdx.x;
    int n0  = blockIdx.x * 64;
    int k80 = blockIdx.y * 32;

    #pragma unroll
    for (int i = 0; i < 8; ++i) {
        int idx = i * 256 + tid;
        int k8l = idx >> 6;
        int nl  = idx & 63;
        int k8  = k80 + k8l;
        int nn  = n0 + nl;
        uint32_t w = qw[(size_t)k8 * N_DIM + nn];
        int g = gidx[k8 * 8];
        uint32_t zw = qz[(size_t)g * (N_DIM / 8) + (nn >> 3)];
        int z = (int)((zw >> ((nn & 7) * 4)) & 0xFu);
        uint64_t o = 0;
        #pragma unroll
        for (int j = 0; j < 8; ++j) {
            int wv = (int)((w >> (4 * j)) & 0xFu);
            o |= (uint64_t)(uint8_t)(signed char)(wv - z) << (8 * j);
        }
        *(uint64_t*)&lds[nl * DLROW + k8l * 8] = o;
    }
    __syncthreads();
    #pragma unroll
    for (int i = 0; i < 4; ++i) {
        int idx = i * 256 + tid;
        int row = idx >> 4;
        int c   = idx & 15;
        i32x4 v = *(const i32x4*)&lds[row * DLROW + c * 16];
        *(i32x4*)&wt[(size_t)(n0 + row) * K_DIM + k80 * 8 + c * 16] = v;
    }
}

// ---------------- kernel 3: int8 GEMM, 256x128 tile, 4-phase pipelined ----------------
// 512 thr = 8 waves (4m x 2n), per-wave 64x64. BK=128 = one scale group.
// 4 phases per iteration (2 K-tiles): phase = one B-half (nq) x full A x full K.
// Per phase per wave: 16 MFMA (mt=0..3, n2=0..1, 2 chained k-steps).
// A-frags read ONCE per tile (held in regs across the tile's 2 phases).
// Deferred rescale: phase p's locked region = 16 MFMA -> iacc_cur, then
// cvt+fma of iacc_prev (independent -> fills MFMA shadow; in-order issue OK).
// Two iacc sets (iax/iay) ping-pong textually; first rescale is a zero-add;
// final rescale after the loop.
// Staging (tiles +2, double-buffered LDS; regions free per dead-after rule):
//   Ph1: S(t0+2)[cond] + Bset1_b1(t1) + A_b1(t1)x4   (forced: free after Ph4')
//   Ph2: Bset0_b0(t0+2)            [free after Ph1]
//   Ph3: Bset1_b0(t0+2) + A_b0(t0+2)x4 [free after Ph2]
//   Ph4: Bset0_b1(t1+2)            [free after Ph3]
// Counted waits (FIFO-simulated): steady VMW(1) end-Ph2 and end-Ph4 only;
// every staged group >=1.5 phases in flight; tail drains VMW(0) at it=15 Ph2.
#define VMW(n) asm volatile("s_waitcnt vmcnt(" #n ")" ::: "memory")

#define STAGE_A(bufi, t, s, j)                                                   \
    gload16(ga + ((size_t)((s) * 32 + (j) * 128) * K_DIM + (size_t)(t) * 128),   \
            &As[bufi][((((s) * 32 + (j) * 128 + brl)) << 7) + sc * 16])

#define STAGE_B(bufi, t, s)                                                      \
    gload16(gb + ((size_t)((s) * 32) * K_DIM + (size_t)(t) * 128),               \
            &Bs[bufi][((((s) * 32 + brl)) << 7) + sc * 16])

// scales for tile-pair (t, t+1): 1KB, all 8 waves stage identical data (benign;
// keeps per-wave vmcnt uniform). lane<32 -> row t, lane>=32 -> row t+1.
#define STAGE_S(slot, t)                                                         \
    gload16(S + (size_t)((t) + (lane >> 5)) * N_DIM + bn + (lane & 31) * 4,      \
            &Sl[slot][lane * 4])

// rescale prev phase's int acc into facc (independent of current MFMAs)
#define RESC(iacS, svS, snq)                                                     \
    _Pragma("unroll")                                                            \
    for (int mt_ = 0; mt_ < 4; ++mt_) {                                          \
        _Pragma("unroll")                                                        \
        for (int n2_ = 0; n2_ < 2; ++n2_) {                                      \
            float ss_ = svS[(snq) * 2 + n2_];                                    \
            _Pragma("unroll")                                                    \
            for (int r_ = 0; r_ < 4; ++r_)                                       \
                facc[mt_][(snq) * 2 + n2_][r_] +=                                \
                    (float)iacS[mt_][n2_][r_] * ss_;                             \
        }                                                                        \
    }

#define PHASE(bufi, nq, TSTART, svN, iacW, iacR, svR, snq, STG, TAIL) do {       \
    if (TSTART) {                                                                \
        _Pragma("unroll")                                                        \
        for (int nt_ = 0; nt_ < 4; ++nt_)                                        \
            svN[nt_] = Sl[pp][(bufi) * 128 + wave_n * 64 + nt_ * 16 + l15];      \
        _Pragma("unroll")                                                        \
        for (int mt_ = 0; mt_ < 4; ++mt_) {                                      \
            const signed char* p_ =                                              \
                &As[bufi][(wave_m * 64 + mt_ * 16 + l15) << 7];                  \
            afr[mt_][0] = *(const i32x4*)(p_ + c0);                              \
            afr[mt_][1] = *(const i32x4*)(p_ + c1);                              \
        }                                                                        \
    }                                                                            \
    _Pragma("unroll")                                                            \
    for (int n2_ = 0; n2_ < 2; ++n2_) {                                          \
        const signed char* p_ =                                                  \
            &Bs[bufi][(wave_n * 64 + ((nq) * 2 + n2_) * 16 + l15) << 7];         \
        bfr[n2_][0] = *(const i32x4*)(p_ + c0);                                  \
        bfr[n2_][1] = *(const i32x4*)(p_ + c1);                                  \
    }                                                                            \
    STG;                                                                         \
    __builtin_amdgcn_s_barrier();                                                \
    asm volatile("s_waitcnt lgkmcnt(0)" ::: "memory");                           \
    __builtin_amdgcn_s_setprio(1);                                               \
    _Pragma("unroll")                                                            \
    for (int mt_ = 0; mt_ < 4; ++mt_) {                                          \
        _Pragma("unroll")                                                        \
        for (int n2_ = 0; n2_ < 2; ++n2_) {                                      \
            i32x4 t0_ = __builtin_amdgcn_mfma_i32_16x16x64_i8(                   \
                afr[mt_][0], bfr[n2_][0], (i32x4){0, 0, 0, 0}, 0, 0, 0);         \
            iacW[mt_][n2_] = __builtin_amdgcn_mfma_i32_16x16x64_i8(              \
                afr[mt_][1], bfr[n2_][1], t0_, 0, 0, 0);                         \
        }                                                                        \
    }                                                                            \
    RESC(iacR, svR, snq);                                                        \
    __builtin_amdgcn_s_setprio(0);                                               \
    TAIL;                                                                        \
    __builtin_amdgcn_s_barrier();                                                \
    __builtin_amdgcn_sched_barrier(0);                                           \
} while (0)

__global__ __launch_bounds__(512)
__attribute__((amdgpu_waves_per_eu(2, 2)))
void gemm_i8(const signed char* __restrict__ A,
             const signed char* __restrict__ B,
             const float* __restrict__ S,
             const float* __restrict__ XS,
             float* __restrict__ C) {
    __shared__ __align__(16) signed char As[2][256 * 128];   // 64 KB
    __shared__ __align__(16) signed char Bs[2][128 * 128];   // 32 KB
    __shared__ __align__(16) float Sl[2][256];               //  2 KB

    const int tid  = threadIdx.x;
    const int lane = tid & 63;
    const int wid  = tid >> 6;          // 0..7
    const int l15  = lane & 15;
    const int quad = lane >> 4;         // 0..3
    const int wave_m = wid >> 1;        // 0..3
    const int wave_n = wid & 1;         // 0..1
    const int h  = l15 & 7;
    const int c0 = (quad ^ h) * 16;
    const int c1 = ((4 + quad) ^ h) * 16;

    // XCD-aware swizzle: 1024 blocks, 128 contiguous tiles per XCD
    int bid = blockIdx.x;
    int swz = (bid & 7) * 128 + (bid >> 3);
    int bm = (swz >> 5) * 256;          // 32 m-tiles
    int bn = (swz & 31) * 128;          // 32 n-tiles

    // staging: thread t covers row brl(+set offsets), 16B chunk sc; global chunk
    // pre-swizzled so LDS stays linear while fragment reads use chunk^(row&7)
    const int sr  = tid >> 3;                        // 0..63
    const int sc  = tid & 7;
    const int gch = sc ^ (sr & 7);
    const int brl = (sr & 31) + ((sr >> 5) << 6);    // rows [0,32) u [64,96)
    const signed char* ga = A + (size_t)(bm + brl) * K_DIM + gch * 16;
    const signed char* gb = B + (size_t)(bn + brl) * K_DIM + gch * 16;

    f32x4 facc[4][4];
    i32x4 afr[4][2], bfr[2][2];
    i32x4 iax[4][2], iay[4][2];
    float sva[4], svb[4];
    #pragma unroll
    for (int i = 0; i < 4; ++i) {
        #pragma unroll
        for (int j = 0; j < 4; ++j)
            facc[i][j] = (f32x4){0.f, 0.f, 0.f, 0.f};
        iay[i][0] = (i32x4){0, 0, 0, 0};
        iay[i][1] = (i32x4){0, 0, 0, 0};
    }
    svb[0] = svb[1] = svb[2] = svb[3] = 0.f;   // first Ph1 rescale = zero-add

    // prologue: S(0,1)->slot0; t0=0 full (B both sets + A); Bset0_b1(1).
    // FIFO: leave only Bset0_b1(1) in flight (awaited end-Ph2(0)).
    STAGE_S(0, 0);
    STAGE_B(0, 0, 0);
    STAGE_B(0, 0, 1);
    STAGE_A(0, 0, 0, 0); STAGE_A(0, 0, 0, 1);
    STAGE_A(0, 0, 1, 0); STAGE_A(0, 0, 1, 1);
    STAGE_B(1, 1, 0);
    VMW(1);
    __builtin_amdgcn_s_barrier();
    __builtin_amdgcn_sched_barrier(0);

    #pragma clang loop unroll(disable)
    for (int it = 0; it < 16; ++it) {
        const int pp  = it & 1;
        const int t0k = 2 * it;
        const int t1k = 2 * it + 1;
        const bool nl = (it < 15);

        // Ph1: buf0 tile-start (nq0); writes iax; rescales iay (prev Ph4, nq1, svb)
        PHASE(0, 0, 1, sva, iax, iay, svb, 1,
              { if (nl) { STAGE_S(pp ^ 1, t0k + 2); }
                STAGE_B(1, t1k, 1);
                STAGE_A(1, t1k, 0, 0); STAGE_A(1, t1k, 0, 1);
                STAGE_A(1, t1k, 1, 0); STAGE_A(1, t1k, 1, 1); },
              {});
        // Ph2: buf0 nq1; writes iay; rescales iax (Ph1, nq0, sva)
        PHASE(0, 1, 0, sva, iay, iax, sva, 0,
              { if (nl) { STAGE_B(0, t0k + 2, 0); } },
              { if (nl) { VMW(1); } else { VMW(0); } });
        // Ph3: buf1 tile-start (nq0); writes iax; rescales iay (Ph2, nq1, sva)
        PHASE(1, 0, 1, svb, iax, iay, sva, 1,
              { if (nl) { STAGE_B(0, t0k + 2, 1);
                          STAGE_A(0, t0k + 2, 0, 0); STAGE_A(0, t0k + 2, 0, 1);
                          STAGE_A(0, t0k + 2, 1, 0); STAGE_A(0, t0k + 2, 1, 1); } },
              {});
        // Ph4: buf1 nq1; writes iay; rescales iax (Ph3, nq0, svb)
        PHASE(1, 1, 0, svb, iay, iax, svb, 0,
              { if (nl) { STAGE_B(1, t1k + 2, 0); } },
              { if (nl) { VMW(1); } });
    }
    // final rescale: Ph4(15)'s iay (buf1, nq1, svb)
    RESC(iay, svb, 1);

    // epilogue: C/D layout col = lane&15 (n), row = quad*4 + r (m)
    #pragma unroll
    for (int mt = 0; mt < 4; ++mt) {
        int row0 = bm + wave_m * 64 + mt * 16 + quad * 4;
        float4 xsv = *(const float4*)(XS + row0);
        #pragma unroll
        for (int nt = 0; nt < 4; ++nt) {
            int col = bn + wave_n * 64 + nt * 16 + l15;
            C[(size_t)(row0 + 0) * N_DIM + col] = facc[mt][nt][0] * xsv.x;
            C[(size_t)(row0 + 1) * N_DIM + col] = facc[mt][nt][1] * xsv.y;
            C[(size_t)(row0 + 2) * N_DIM + col] = facc[mt][nt][2] * xsv.z;
            C[(size_t)(row0 + 3) * N_DIM + col] = facc[mt][nt][3] * xsv.w;
        }
    }
}

extern "C" void kernel_launch(void* const* d_in, const int* in_sizes, int n_in,
                              void* d_out, int out_size, void* d_ws, size_t ws_size,
                              hipStream_t stream) {
    const float*    x    = (const float*)d_in[0];
    const uint32_t* qw   = (const uint32_t*)d_in[1];
    const uint32_t* qz   = (const uint32_t*)d_in[2];
    const float*    sc   = (const float*)d_in[3];
    const int*      gidx = (const int*)d_in[4];
    float* out = (float*)d_out;

    signed char* xq = (signed char*)d_ws;                          // [M][K] int8, 32 MB
    signed char* wt = xq + (size_t)M_DIM * K_DIM;                  // [N][K] int8, 16 MB
    float*       xs = (float*)(wt + (size_t)N_DIM * K_DIM);        // [M] fp32

    conv_x_i8<<<dim3(M_DIM), 256, 0, stream>>>(x, (int*)xq, xs);
    dequant_i8<<<dim3(N_DIM / 64, K_DIM / 256), 256, 0, stream>>>(qw, qz, gidx, wt);
    gemm_i8<<<dim3(1024), dim3(512), 0, stream>>>(xq, wt, sc, xs, out);
}

// Round 4
// 474.883 us; speedup vs baseline: 1.1317x; 1.1317x over previous
//
#include <hip/hip_runtime.h>
#include <stdint.h>

#define M_DIM 8192
#define K_DIM 4096
#define N_DIM 4096

typedef int   i32x4 __attribute__((ext_vector_type(4)));
typedef float f32x4 __attribute__((ext_vector_type(4)));

// async global -> LDS, 16B per active lane; LDS dest = wave-uniform base + lane*16
__device__ __forceinline__ void gload16(const void* g, void* l) {
    __builtin_amdgcn_global_load_lds(
        (const __attribute__((address_space(1))) void*)g,
        (__attribute__((address_space(3))) void*)l,
        16, 0, 0);
}

// ---------------- kernel 1: x fp32 -> int8 with per-row scale ----------------
__global__ __launch_bounds__(256) void conv_x_i8(const float* __restrict__ x,
                                                 int* __restrict__ xq,
                                                 float* __restrict__ xs) {
    int m = blockIdx.x, tid = threadIdx.x;
    const float* row = x + (size_t)m * K_DIM;
    float4 v[4];
    float mx = 0.f;
    #pragma unroll
    for (int i = 0; i < 4; ++i) {
        v[i] = *(const float4*)(row + i * 1024 + tid * 4);
        mx = fmaxf(mx, fmaxf(fmaxf(fabsf(v[i].x), fabsf(v[i].y)),
                             fmaxf(fabsf(v[i].z), fabsf(v[i].w))));
    }
    #pragma unroll
    for (int o = 32; o > 0; o >>= 1) mx = fmaxf(mx, __shfl_xor(mx, o, 64));
    __shared__ float red[4];
    if ((tid & 63) == 0) red[tid >> 6] = mx;
    __syncthreads();
    mx = fmaxf(fmaxf(red[0], red[1]), fmaxf(red[2], red[3]));
    mx = fmaxf(mx, 1e-20f);
    float inv = 127.f / mx;
    if (tid == 0) xs[m] = mx * (1.f / 127.f);
    #pragma unroll
    for (int i = 0; i < 4; ++i) {
        int q0 = (int)__builtin_rintf(v[i].x * inv);
        int q1 = (int)__builtin_rintf(v[i].y * inv);
        int q2 = (int)__builtin_rintf(v[i].z * inv);
        int q3 = (int)__builtin_rintf(v[i].w * inv);
        uint32_t p = (uint32_t)(q0 & 255) | ((uint32_t)(q1 & 255) << 8) |
                     ((uint32_t)(q2 & 255) << 16) | ((uint32_t)q3 << 24);
        xq[(size_t)m * (K_DIM / 4) + i * 256 + tid] = (int)p;
    }
}

// ---------------- kernel 2: dequant -> Wt int8 [N, K], value (w - z) ----------------
#define DLROW 272   // 256 + 16 bytes pad
__global__ __launch_bounds__(256) void dequant_i8(const uint32_t* __restrict__ qw,
                                                  const uint32_t* __restrict__ qz,
                                                  const int* __restrict__ gidx,
                                                  signed char* __restrict__ wt) {
    __shared__ __align__(16) unsigned char lds[64 * DLROW];
    int tid = threadIdx.x;
    int n0  = blockIdx.x * 64;
    int k80 = blockIdx.y * 32;

    #pragma unroll
    for (int i = 0; i < 8; ++i) {
        int idx = i * 256 + tid;
        int k8l = idx >> 6;
        int nl  = idx & 63;
        int k8  = k80 + k8l;
        int nn  = n0 + nl;
        uint32_t w = qw[(size_t)k8 * N_DIM + nn];
        int g = gidx[k8 * 8];
        uint32_t zw = qz[(size_t)g * (N_DIM / 8) + (nn >> 3)];
        int z = (int)((zw >> ((nn & 7) * 4)) & 0xFu);
        uint64_t o = 0;
        #pragma unroll
        for (int j = 0; j < 8; ++j) {
            int wv = (int)((w >> (4 * j)) & 0xFu);
            o |= (uint64_t)(uint8_t)(signed char)(wv - z) << (8 * j);
        }
        *(uint64_t*)&lds[nl * DLROW + k8l * 8] = o;
    }
    __syncthreads();
    #pragma unroll
    for (int i = 0; i < 4; ++i) {
        int idx = i * 256 + tid;
        int row = idx >> 4;
        int c   = idx & 15;
        i32x4 v = *(const i32x4*)&lds[row * DLROW + c * 16];
        *(i32x4*)&wt[(size_t)(n0 + row) * K_DIM + k80 * 8 + c * 16] = v;
    }
}

// ---------------- kernel 3: int8 GEMM, 256x128 tile, 4-phase pipelined ----------------
// 512 thr = 8 waves (4m x 2n), per-wave 64x64. BK=128 = one scale group.
// 4 phases / iter (2 K-tiles); phase = one B-half (nq), full A, full K.
// Rolling-window deferred rescale (register-lean; arch alloc capped at 128):
//   ia[4] window (16 regs). Step q in 0..7: RESC the quad written 4 pairs ago
//   (8 MFMAs ~160cy in flight > MFMA latency -> no dep stall), then MFMA pair
//   overwrites that slot. Steps 0-3 retire PREV phase's quads (mt 2-3, prev
//   nq/scales; zero-add on first phase); steps 4-7 retire this phase's 0-3.
//   A-frags are a 2-entry window (read mt 0-1 at head, mt 2-3 mid-phase).
//   sched_barrier(0) per step pins the interleave (no rescale sinking).
// Staging/vmcnt/barrier skeleton identical to rounds 2/3 (HW-validated):
//   Ph1: S[cond] + Bset1_b1(t1) + A_b1(t1)x4    Ph2: Bset0_b0(t0+2), VMW(1)
//   Ph3: Bset1_b0(t0+2) + A_b0(t0+2)x4         Ph4: Bset0_b1(t1+2), VMW(1)
#define VMW(n) asm volatile("s_waitcnt vmcnt(" #n ")" ::: "memory")

#define STAGE_A(bufi, t, s, j)                                                   \
    gload16(ga + ((size_t)((s) * 32 + (j) * 128) * K_DIM + (size_t)(t) * 128),   \
            &As[bufi][((((s) * 32 + (j) * 128 + brl)) << 7) + sc * 16])

#define STAGE_B(bufi, t, s)                                                      \
    gload16(gb + ((size_t)((s) * 32) * K_DIM + (size_t)(t) * 128),               \
            &Bs[bufi][((((s) * 32 + brl)) << 7) + sc * 16])

// scales for tile-pair (t, t+1): 1KB, all 8 waves stage identical data (benign;
// keeps per-wave vmcnt uniform). lane<32 -> row t, lane>=32 -> row t+1.
#define STAGE_S(slot, t)                                                         \
    gload16(S + (size_t)((t) + (lane >> 5)) * N_DIM + bn + (lane & 31) * 4,      \
            &Sl[slot][lane * 4])

// retire window slot w into facc[omt][onq*2+on2] with scale set osv
#define RESC1(w, omt, onq, on2, osv) do {                                        \
    float ss_ = osv[(onq) * 2 + (on2)];                                          \
    _Pragma("unroll")                                                            \
    for (int r_ = 0; r_ < 4; ++r_)                                               \
        facc[omt][(onq) * 2 + (on2)][r_] += (float)ia[w][r_] * ss_;              \
} while (0)

// MFMA pair (full K=128 of this tile) into window slot w
#define MSTEP(w, nmt, nn2) do {                                                  \
    i32x4 t0_ = __builtin_amdgcn_mfma_i32_16x16x64_i8(                           \
        af[(nmt) & 1][0], bf[nn2][0], (i32x4){0, 0, 0, 0}, 0, 0, 0);             \
    ia[w] = __builtin_amdgcn_mfma_i32_16x16x64_i8(                               \
        af[(nmt) & 1][1], bf[nn2][1], t0_, 0, 0, 0);                             \
} while (0)

#define LDA(bufi, mt) do {                                                       \
    const signed char* p_ = &As[bufi][(wave_m * 64 + (mt) * 16 + l15) << 7];     \
    af[(mt) & 1][0] = *(const i32x4*)(p_ + c0);                                  \
    af[(mt) & 1][1] = *(const i32x4*)(p_ + c1);                                  \
} while (0)

#define SB() __builtin_amdgcn_sched_barrier(0)

#define PHASE(bufi, nq, TSTART, svC, svP, pnq, STG, TAIL) do {                   \
    if (TSTART) {                                                                \
        _Pragma("unroll")                                                        \
        for (int nt_ = 0; nt_ < 4; ++nt_)                                        \
            svC[nt_] = Sl[pp][(bufi) * 128 + wave_n * 64 + nt_ * 16 + l15];      \
    }                                                                            \
    LDA(bufi, 0); LDA(bufi, 1);                                                  \
    _Pragma("unroll")                                                            \
    for (int n2_ = 0; n2_ < 2; ++n2_) {                                          \
        const signed char* p_ =                                                  \
            &Bs[bufi][(wave_n * 64 + ((nq) * 2 + n2_) * 16 + l15) << 7];         \
        bf[n2_][0] = *(const i32x4*)(p_ + c0);                                   \
        bf[n2_][1] = *(const i32x4*)(p_ + c1);                                   \
    }                                                                            \
    STG;                                                                         \
    __builtin_amdgcn_s_barrier();                                                \
    asm volatile("s_waitcnt lgkmcnt(0)" ::: "memory");                           \
    __builtin_amdgcn_s_setprio(1);                                               \
    RESC1(0, 2, pnq, 0, svP); MSTEP(0, 0, 0); SB();                              \
    RESC1(1, 2, pnq, 1, svP); MSTEP(1, 0, 1); SB();                              \
    RESC1(2, 3, pnq, 0, svP); MSTEP(2, 1, 0); SB();                              \
    RESC1(3, 3, pnq, 1, svP); MSTEP(3, 1, 1); SB();                              \
    LDA(bufi, 2); LDA(bufi, 3);                                                  \
    RESC1(0, 0, nq, 0, svC); MSTEP(0, 2, 0); SB();                               \
    RESC1(1, 0, nq, 1, svC); MSTEP(1, 2, 1); SB();                               \
    RESC1(2, 1, nq, 0, svC); MSTEP(2, 3, 0); SB();                               \
    RESC1(3, 1, nq, 1, svC); MSTEP(3, 3, 1);                                     \
    __builtin_amdgcn_s_setprio(0);                                               \
    TAIL;                                                                        \
    __builtin_amdgcn_s_barrier();                                                \
    __builtin_amdgcn_sched_barrier(0);                                           \
} while (0)

__global__ __launch_bounds__(512, 2)
void gemm_i8(const signed char* __restrict__ A,
             const signed char* __restrict__ B,
             const float* __restrict__ S,
             const float* __restrict__ XS,
             float* __restrict__ C) {
    __shared__ __align__(16) signed char As[2][256 * 128];   // 64 KB
    __shared__ __align__(16) signed char Bs[2][128 * 128];   // 32 KB
    __shared__ __align__(16) float Sl[2][256];               //  2 KB

    const int tid  = threadIdx.x;
    const int lane = tid & 63;
    const int wid  = tid >> 6;          // 0..7
    const int l15  = lane & 15;
    const int quad = lane >> 4;         // 0..3
    const int wave_m = wid >> 1;        // 0..3
    const int wave_n = wid & 1;         // 0..1
    const int h  = l15 & 7;
    const int c0 = (quad ^ h) * 16;
    const int c1 = ((4 + quad) ^ h) * 16;

    // XCD-aware swizzle: 1024 blocks, 128 contiguous tiles per XCD
    int bid = blockIdx.x;
    int swz = (bid & 7) * 128 + (bid >> 3);
    int bm = (swz >> 5) * 256;          // 32 m-tiles
    int bn = (swz & 31) * 128;          // 32 n-tiles

    // staging: thread t covers row brl(+set offsets), 16B chunk sc; global chunk
    // pre-swizzled so LDS stays linear while fragment reads use chunk^(row&7)
    const int sr  = tid >> 3;                        // 0..63
    const int sc  = tid & 7;
    const int gch = sc ^ (sr & 7);
    const int brl = (sr & 31) + ((sr >> 5) << 6);    // rows [0,32) u [64,96)
    const signed char* ga = A + (size_t)(bm + brl) * K_DIM + gch * 16;
    const signed char* gb = B + (size_t)(bn + brl) * K_DIM + gch * 16;

    f32x4 facc[4][4];
    i32x4 af[2][2], bf[2][2];
    i32x4 ia[4];
    float sva[4], svb[4];
    #pragma unroll
    for (int i = 0; i < 4; ++i) {
        #pragma unroll
        for (int j = 0; j < 4; ++j)
            facc[i][j] = (f32x4){0.f, 0.f, 0.f, 0.f};
        ia[i] = (i32x4){0, 0, 0, 0};
    }
    svb[0] = svb[1] = svb[2] = svb[3] = 0.f;   // first-phase retire = zero-add

    // prologue: S(0,1)->slot0; t0=0 full (B both sets + A); Bset0_b1(1).
    // FIFO: leave only Bset0_b1(1) in flight (awaited end-Ph2(0)).
    STAGE_S(0, 0);
    STAGE_B(0, 0, 0);
    STAGE_B(0, 0, 1);
    STAGE_A(0, 0, 0, 0); STAGE_A(0, 0, 0, 1);
    STAGE_A(0, 0, 1, 0); STAGE_A(0, 0, 1, 1);
    STAGE_B(1, 1, 0);
    VMW(1);
    __builtin_amdgcn_s_barrier();
    __builtin_amdgcn_sched_barrier(0);

    #pragma clang loop unroll(disable)
    for (int it = 0; it < 16; ++it) {
        const int pp  = it & 1;
        const int t0k = 2 * it;
        const int t1k = 2 * it + 1;
        const bool nl = (it < 15);

        // Ph1: buf0 nq0; retires prev Ph4 (buf1, nq1, svb of prev iter)
        PHASE(0, 0, 1, sva, svb, 1,
              { if (nl) { STAGE_S(pp ^ 1, t0k + 2); }
                STAGE_B(1, t1k, 1);
                STAGE_A(1, t1k, 0, 0); STAGE_A(1, t1k, 0, 1);
                STAGE_A(1, t1k, 1, 0); STAGE_A(1, t1k, 1, 1); },
              {});
        // Ph2: buf0 nq1; retires Ph1 (nq0, sva)
        PHASE(0, 1, 0, sva, sva, 0,
              { if (nl) { STAGE_B(0, t0k + 2, 0); } },
              { if (nl) { VMW(1); } else { VMW(0); } });
        // Ph3: buf1 nq0; retires Ph2 (nq1, sva)
        PHASE(1, 0, 1, svb, sva, 1,
              { if (nl) { STAGE_B(0, t0k + 2, 1);
                          STAGE_A(0, t0k + 2, 0, 0); STAGE_A(0, t0k + 2, 0, 1);
                          STAGE_A(0, t0k + 2, 1, 0); STAGE_A(0, t0k + 2, 1, 1); } },
              {});
        // Ph4: buf1 nq1; retires Ph3 (nq0, svb)
        PHASE(1, 1, 0, svb, svb, 0,
              { if (nl) { STAGE_B(1, t1k + 2, 0); } },
              { if (nl) { VMW(1); } });
    }
    // final drain: Ph4(15)'s quads 4..7 live in ia[0..3] (mt 2-3, nq1, svb)
    RESC1(0, 2, 1, 0, svb);
    RESC1(1, 2, 1, 1, svb);
    RESC1(2, 3, 1, 0, svb);
    RESC1(3, 3, 1, 1, svb);

    // epilogue: C/D layout col = lane&15 (n), row = quad*4 + r (m)
    #pragma unroll
    for (int mt = 0; mt < 4; ++mt) {
        int row0 = bm + wave_m * 64 + mt * 16 + quad * 4;
        float4 xsv = *(const float4*)(XS + row0);
        #pragma unroll
        for (int nt = 0; nt < 4; ++nt) {
            int col = bn + wave_n * 64 + nt * 16 + l15;
            C[(size_t)(row0 + 0) * N_DIM + col] = facc[mt][nt][0] * xsv.x;
            C[(size_t)(row0 + 1) * N_DIM + col] = facc[mt][nt][1] * xsv.y;
            C[(size_t)(row0 + 2) * N_DIM + col] = facc[mt][nt][2] * xsv.z;
            C[(size_t)(row0 + 3) * N_DIM + col] = facc[mt][nt][3] * xsv.w;
        }
    }
}

extern "C" void kernel_launch(void* const* d_in, const int* in_sizes, int n_in,
                              void* d_out, int out_size, void* d_ws, size_t ws_size,
                              hipStream_t stream) {
    const float*    x    = (const float*)d_in[0];
    const uint32_t* qw   = (const uint32_t*)d_in[1];
    const uint32_t* qz   = (const uint32_t*)d_in[2];
    const float*    sc   = (const float*)d_in[3];
    const int*      gidx = (const int*)d_in[4];
    float* out = (float*)d_out;

    signed char* xq = (signed char*)d_ws;                          // [M][K] int8, 32 MB
    signed char* wt = xq + (size_t)M_DIM * K_DIM;                  // [N][K] int8, 16 MB
    float*       xs = (float*)(wt + (size_t)N_DIM * K_DIM);        // [M] fp32

    conv_x_i8<<<dim3(M_DIM), 256, 0, stream>>>(x, (int*)xq, xs);
    dequant_i8<<<dim3(N_DIM / 64, K_DIM / 256), 256, 0, stream>>>(qw, qz, gidx, wt);
    gemm_i8<<<dim3(1024), dim3(512), 0, stream>>>(xq, wt, sc, xs, out);
}

// Round 5
// 472.512 us; speedup vs baseline: 1.1374x; 1.0050x over previous
//
#include <hip/hip_runtime.h>
#include <stdint.h>

#define M_DIM 8192
#define K_DIM 4096
#define N_DIM 4096

typedef int   i32x4 __attribute__((ext_vector_type(4)));
typedef float f32x4 __attribute__((ext_vector_type(4)));

// async global -> LDS, 16B per active lane; LDS dest = wave-uniform base + lane*16
__device__ __forceinline__ void gload16(const void* g, void* l) {
    __builtin_amdgcn_global_load_lds(
        (const __attribute__((address_space(1))) void*)g,
        (__attribute__((address_space(3))) void*)l,
        16, 0, 0);
}

// ---------------- kernel 1: x fp32 -> int8 with per-row scale ----------------
__global__ __launch_bounds__(256) void conv_x_i8(const float* __restrict__ x,
                                                 int* __restrict__ xq,
                                                 float* __restrict__ xs) {
    int m = blockIdx.x, tid = threadIdx.x;
    const float* row = x + (size_t)m * K_DIM;
    float4 v[4];
    float mx = 0.f;
    #pragma unroll
    for (int i = 0; i < 4; ++i) {
        v[i] = *(const float4*)(row + i * 1024 + tid * 4);
        mx = fmaxf(mx, fmaxf(fmaxf(fabsf(v[i].x), fabsf(v[i].y)),
                             fmaxf(fabsf(v[i].z), fabsf(v[i].w))));
    }
    #pragma unroll
    for (int o = 32; o > 0; o >>= 1) mx = fmaxf(mx, __shfl_xor(mx, o, 64));
    __shared__ float red[4];
    if ((tid & 63) == 0) red[tid >> 6] = mx;
    __syncthreads();
    mx = fmaxf(fmaxf(red[0], red[1]), fmaxf(red[2], red[3]));
    mx = fmaxf(mx, 1e-20f);
    float inv = 127.f / mx;
    if (tid == 0) xs[m] = mx * (1.f / 127.f);
    #pragma unroll
    for (int i = 0; i < 4; ++i) {
        int q0 = (int)__builtin_rintf(v[i].x * inv);
        int q1 = (int)__builtin_rintf(v[i].y * inv);
        int q2 = (int)__builtin_rintf(v[i].z * inv);
        int q3 = (int)__builtin_rintf(v[i].w * inv);
        uint32_t p = (uint32_t)(q0 & 255) | ((uint32_t)(q1 & 255) << 8) |
                     ((uint32_t)(q2 & 255) << 16) | ((uint32_t)q3 << 24);
        xq[(size_t)m * (K_DIM / 4) + i * 256 + tid] = (int)p;
    }
}

// ---------------- kernel 2: dequant -> Wt int8 [N, K], value (w - z) ----------------
#define DLROW 272   // 256 + 16 bytes pad
__global__ __launch_bounds__(256) void dequant_i8(const uint32_t* __restrict__ qw,
                                                  const uint32_t* __restrict__ qz,
                                                  const int* __restrict__ gidx,
                                                  signed char* __restrict__ wt) {
    __shared__ __align__(16) unsigned char lds[64 * DLROW];
    int tid = threadIdx.x;
    int n0  = blockIdx.x * 64;
    int k80 = blockIdx.y * 32;

    #pragma unroll
    for (int i = 0; i < 8; ++i) {
        int idx = i * 256 + tid;
        int k8l = idx >> 6;
        int nl  = idx & 63;
        int k8  = k80 + k8l;
        int nn  = n0 + nl;
        uint32_t w = qw[(size_t)k8 * N_DIM + nn];
        int g = gidx[k8 * 8];
        uint32_t zw = qz[(size_t)g * (N_DIM / 8) + (nn >> 3)];
        int z = (int)((zw >> ((nn & 7) * 4)) & 0xFu);
        uint64_t o = 0;
        #pragma unroll
        for (int j = 0; j < 8; ++j) {
            int wv = (int)((w >> (4 * j)) & 0xFu);
            o |= (uint64_t)(uint8_t)(signed char)(wv - z) << (8 * j);
        }
        *(uint64_t*)&lds[nl * DLROW + k8l * 8] = o;
    }
    __syncthreads();
    #pragma unroll
    for (int i = 0; i < 4; ++i) {
        int idx = i * 256 + tid;
        int row = idx >> 4;
        int c   = idx & 15;
        i32x4 v = *(const i32x4*)&lds[row * DLROW + c * 16];
        *(i32x4*)&wt[(size_t)(n0 + row) * K_DIM + k80 * 8 + c * 16] = v;
    }
}

// ---------------- kernel 3: int8 GEMM, 256x128 tile, 4-phase pipelined ----------------
// 512 thr = 8 waves (4m x 2n), per-wave 64x64. BK=128 = one scale group.
// 4 phases / iter (2 K-tiles); phase = one B-half (nq), full A, full K.
// Rolling-window deferred rescale (ia[4], 16 regs): step q retires the quad
// written 4 MFMA-pairs earlier, then overwrites the slot. sched_barrier per
// step pins the interleave (keeps regalloc spill-free; round-4 verified).
// ROUND-5 CHANGE: single barrier per phase (the pre-MFMA barrier removed).
// Rationale (r4 PMC): per-phase LDS pipe = 96 ds_read_b128 x 12cy ~ 1150cy
// (CU-shared), MFMA = 653cy; two barriers SERIALIZED them -> 2494cy phases
// (MfmaUtil 21%). Per-wave lgkmcnt(0) already orders own reads before own
// MFMAs; one barrier per phase still separates all reads of a region from
// the (>=1-phase-later) staging writes into it, and the TAIL vmcnt before
// the barrier still guarantees all waves' slices landed before next phase
// reads. Waves now drift: one wave's MFMA overlaps another's LDS reads ->
// phase ~ max(LDS, MFMA) instead of sum.
// Staging schedule (unchanged, HW-validated rounds 2-4):
//   Ph1: S[cond] + Bset1_b1(t1) + A_b1(t1)x4    Ph2: Bset0_b0(t0+2), VMW(1)
//   Ph3: Bset1_b0(t0+2) + A_b0(t0+2)x4         Ph4: Bset0_b1(t1+2), VMW(1)
#define VMW(n) asm volatile("s_waitcnt vmcnt(" #n ")" ::: "memory")

#define STAGE_A(bufi, t, s, j)                                                   \
    gload16(ga + ((size_t)((s) * 32 + (j) * 128) * K_DIM + (size_t)(t) * 128),   \
            &As[bufi][((((s) * 32 + (j) * 128 + brl)) << 7) + sc * 16])

#define STAGE_B(bufi, t, s)                                                      \
    gload16(gb + ((size_t)((s) * 32) * K_DIM + (size_t)(t) * 128),               \
            &Bs[bufi][((((s) * 32 + brl)) << 7) + sc * 16])

// scales for tile-pair (t, t+1): 1KB, all 8 waves stage identical data (benign;
// keeps per-wave vmcnt uniform). lane<32 -> row t, lane>=32 -> row t+1.
#define STAGE_S(slot, t)                                                         \
    gload16(S + (size_t)((t) + (lane >> 5)) * N_DIM + bn + (lane & 31) * 4,      \
            &Sl[slot][lane * 4])

// retire window slot w into facc[omt][onq*2+on2] with scale set osv
#define RESC1(w, omt, onq, on2, osv) do {                                        \
    float ss_ = osv[(onq) * 2 + (on2)];                                          \
    _Pragma("unroll")                                                            \
    for (int r_ = 0; r_ < 4; ++r_)                                               \
        facc[omt][(onq) * 2 + (on2)][r_] += (float)ia[w][r_] * ss_;              \
} while (0)

// MFMA pair (full K=128 of this tile) into window slot w
#define MSTEP(w, nmt, nn2) do {                                                  \
    i32x4 t0_ = __builtin_amdgcn_mfma_i32_16x16x64_i8(                           \
        af[(nmt) & 1][0], bf[nn2][0], (i32x4){0, 0, 0, 0}, 0, 0, 0);             \
    ia[w] = __builtin_amdgcn_mfma_i32_16x16x64_i8(                               \
        af[(nmt) & 1][1], bf[nn2][1], t0_, 0, 0, 0);                             \
} while (0)

#define LDA(bufi, mt) do {                                                       \
    const signed char* p_ = &As[bufi][(wave_m * 64 + (mt) * 16 + l15) << 7];     \
    af[(mt) & 1][0] = *(const i32x4*)(p_ + c0);                                  \
    af[(mt) & 1][1] = *(const i32x4*)(p_ + c1);                                  \
} while (0)

#define SB() __builtin_amdgcn_sched_barrier(0)

#define PHASE(bufi, nq, TSTART, svC, svP, pnq, STG, TAIL) do {                   \
    if (TSTART) {                                                                \
        _Pragma("unroll")                                                        \
        for (int nt_ = 0; nt_ < 4; ++nt_)                                        \
            svC[nt_] = Sl[pp][(bufi) * 128 + wave_n * 64 + nt_ * 16 + l15];      \
    }                                                                            \
    LDA(bufi, 0); LDA(bufi, 1);                                                  \
    _Pragma("unroll")                                                            \
    for (int n2_ = 0; n2_ < 2; ++n2_) {                                          \
        const signed char* p_ =                                                  \
            &Bs[bufi][(wave_n * 64 + ((nq) * 2 + n2_) * 16 + l15) << 7];         \
        bf[n2_][0] = *(const i32x4*)(p_ + c0);                                   \
        bf[n2_][1] = *(const i32x4*)(p_ + c1);                                   \
    }                                                                            \
    STG;                                                                         \
    asm volatile("s_waitcnt lgkmcnt(0)" ::: "memory");                           \
    SB();                                                                        \
    __builtin_amdgcn_s_setprio(1);                                               \
    RESC1(0, 2, pnq, 0, svP); MSTEP(0, 0, 0); SB();                              \
    RESC1(1, 2, pnq, 1, svP); MSTEP(1, 0, 1); SB();                              \
    RESC1(2, 3, pnq, 0, svP); MSTEP(2, 1, 0); SB();                              \
    RESC1(3, 3, pnq, 1, svP); MSTEP(3, 1, 1); SB();                              \
    LDA(bufi, 2); LDA(bufi, 3);                                                  \
    RESC1(0, 0, nq, 0, svC); MSTEP(0, 2, 0); SB();                               \
    RESC1(1, 0, nq, 1, svC); MSTEP(1, 2, 1); SB();                               \
    RESC1(2, 1, nq, 0, svC); MSTEP(2, 3, 0); SB();                               \
    RESC1(3, 1, nq, 1, svC); MSTEP(3, 3, 1);                                     \
    __builtin_amdgcn_s_setprio(0);                                               \
    TAIL;                                                                        \
    __builtin_amdgcn_s_barrier();                                                \
    __builtin_amdgcn_sched_barrier(0);                                           \
} while (0)

__global__ __launch_bounds__(512, 2)
void gemm_i8(const signed char* __restrict__ A,
             const signed char* __restrict__ B,
             const float* __restrict__ S,
             const float* __restrict__ XS,
             float* __restrict__ C) {
    __shared__ __align__(16) signed char As[2][256 * 128];   // 64 KB
    __shared__ __align__(16) signed char Bs[2][128 * 128];   // 32 KB
    __shared__ __align__(16) float Sl[2][256];               //  2 KB

    const int tid  = threadIdx.x;
    const int lane = tid & 63;
    const int wid  = tid >> 6;          // 0..7
    const int l15  = lane & 15;
    const int quad = lane >> 4;         // 0..3
    const int wave_m = wid >> 1;        // 0..3
    const int wave_n = wid & 1;         // 0..1
    const int h  = l15 & 7;
    const int c0 = (quad ^ h) * 16;
    const int c1 = ((4 + quad) ^ h) * 16;

    // XCD-aware swizzle: 1024 blocks, 128 contiguous tiles per XCD
    int bid = blockIdx.x;
    int swz = (bid & 7) * 128 + (bid >> 3);
    int bm = (swz >> 5) * 256;          // 32 m-tiles
    int bn = (swz & 31) * 128;          // 32 n-tiles

    // staging: thread t covers row brl(+set offsets), 16B chunk sc; global chunk
    // pre-swizzled so LDS stays linear while fragment reads use chunk^(row&7)
    const int sr  = tid >> 3;                        // 0..63
    const int sc  = tid & 7;
    const int gch = sc ^ (sr & 7);
    const int brl = (sr & 31) + ((sr >> 5) << 6);    // rows [0,32) u [64,96)
    const signed char* ga = A + (size_t)(bm + brl) * K_DIM + gch * 16;
    const signed char* gb = B + (size_t)(bn + brl) * K_DIM + gch * 16;

    f32x4 facc[4][4];
    i32x4 af[2][2], bf[2][2];
    i32x4 ia[4];
    float sva[4], svb[4];
    #pragma unroll
    for (int i = 0; i < 4; ++i) {
        #pragma unroll
        for (int j = 0; j < 4; ++j)
            facc[i][j] = (f32x4){0.f, 0.f, 0.f, 0.f};
        ia[i] = (i32x4){0, 0, 0, 0};
    }
    svb[0] = svb[1] = svb[2] = svb[3] = 0.f;   // first-phase retire = zero-add

    // prologue: S(0,1)->slot0; t0=0 full (B both sets + A); Bset0_b1(1).
    // FIFO: leave only Bset0_b1(1) in flight (awaited end-Ph2(0)).
    STAGE_S(0, 0);
    STAGE_B(0, 0, 0);
    STAGE_B(0, 0, 1);
    STAGE_A(0, 0, 0, 0); STAGE_A(0, 0, 0, 1);
    STAGE_A(0, 0, 1, 0); STAGE_A(0, 0, 1, 1);
    STAGE_B(1, 1, 0);
    VMW(1);
    __builtin_amdgcn_s_barrier();
    __builtin_amdgcn_sched_barrier(0);

    #pragma clang loop unroll(disable)
    for (int it = 0; it < 16; ++it) {
        const int pp  = it & 1;
        const int t0k = 2 * it;
        const int t1k = 2 * it + 1;
        const bool nl = (it < 15);

        // Ph1: buf0 nq0; retires prev Ph4 (buf1, nq1, svb of prev iter)
        PHASE(0, 0, 1, sva, svb, 1,
              { if (nl) { STAGE_S(pp ^ 1, t0k + 2); }
                STAGE_B(1, t1k, 1);
                STAGE_A(1, t1k, 0, 0); STAGE_A(1, t1k, 0, 1);
                STAGE_A(1, t1k, 1, 0); STAGE_A(1, t1k, 1, 1); },
              {});
        // Ph2: buf0 nq1; retires Ph1 (nq0, sva)
        PHASE(0, 1, 0, sva, sva, 0,
              { if (nl) { STAGE_B(0, t0k + 2, 0); } },
              { if (nl) { VMW(1); } else { VMW(0); } });
        // Ph3: buf1 nq0; retires Ph2 (nq1, sva)
        PHASE(1, 0, 1, svb, sva, 1,
              { if (nl) { STAGE_B(0, t0k + 2, 1);
                          STAGE_A(0, t0k + 2, 0, 0); STAGE_A(0, t0k + 2, 0, 1);
                          STAGE_A(0, t0k + 2, 1, 0); STAGE_A(0, t0k + 2, 1, 1); } },
              {});
        // Ph4: buf1 nq1; retires Ph3 (nq0, svb)
        PHASE(1, 1, 0, svb, svb, 0,
              { if (nl) { STAGE_B(1, t1k + 2, 0); } },
              { if (nl) { VMW(1); } });
    }
    // final drain: Ph4(15)'s quads 4..7 live in ia[0..3] (mt 2-3, nq1, svb)
    RESC1(0, 2, 1, 0, svb);
    RESC1(1, 2, 1, 1, svb);
    RESC1(2, 3, 1, 0, svb);
    RESC1(3, 3, 1, 1, svb);

    // epilogue: C/D layout col = lane&15 (n), row = quad*4 + r (m)
    #pragma unroll
    for (int mt = 0; mt < 4; ++mt) {
        int row0 = bm + wave_m * 64 + mt * 16 + quad * 4;
        float4 xsv = *(const float4*)(XS + row0);
        #pragma unroll
        for (int nt = 0; nt < 4; ++nt) {
            int col = bn + wave_n * 64 + nt * 16 + l15;
            C[(size_t)(row0 + 0) * N_DIM + col] = facc[mt][nt][0] * xsv.x;
            C[(size_t)(row0 + 1) * N_DIM + col] = facc[mt][nt][1] * xsv.y;
            C[(size_t)(row0 + 2) * N_DIM + col] = facc[mt][nt][2] * xsv.z;
            C[(size_t)(row0 + 3) * N_DIM + col] = facc[mt][nt][3] * xsv.w;
        }
    }
}

extern "C" void kernel_launch(void* const* d_in, const int* in_sizes, int n_in,
                              void* d_out, int out_size, void* d_ws, size_t ws_size,
                              hipStream_t stream) {
    const float*    x    = (const float*)d_in[0];
    const uint32_t* qw   = (const uint32_t*)d_in[1];
    const uint32_t* qz   = (const uint32_t*)d_in[2];
    const float*    sc   = (const float*)d_in[3];
    const int*      gidx = (const int*)d_in[4];
    float* out = (float*)d_out;

    signed char* xq = (signed char*)d_ws;                          // [M][K] int8, 32 MB
    signed char* wt = xq + (size_t)M_DIM * K_DIM;                  // [N][K] int8, 16 MB
    float*       xs = (float*)(wt + (size_t)N_DIM * K_DIM);        // [M] fp32

    conv_x_i8<<<dim3(M_DIM), 256, 0, stream>>>(x, (int*)xq, xs);
    dequant_i8<<<dim3(N_DIM / 64, K_DIM / 256), 256, 0, stream>>>(qw, qz, gidx, wt);
    gemm_i8<<<dim3(1024), dim3(512), 0, stream>>>(xq, wt, sc, xs, out);
}